// Round 10
// baseline (95.044 us; speedup 1.0000x reference)
//
#include <hip/hip_runtime.h>

// OpenBoundary neighbor list, N=8192, cutoff=5.0, max_neighbours=32.
// Outputs (int32, concat): to_idx[8192][32] | cell_indices[8192][32][3]=0 | actual_max
//
// R10: 2-dispatch version of R9 (77.1us).
//   build (1 block x 1024): LDS hist -> LDS scan -> atomic-free scatter (to d_ws).
//   query (8192 waves, one per point): flattened compact candidate list,
//         ballot-compact, 64-lane bitonic sort (= argwhere ascending-j order),
//         write row; each block zeroes its 1.5KB cell_indices slice and
//         atomicMax's the scalar (finalize folded in; poison<0 = identity).

constexpr int   N     = 8192;
constexpr int   MAXNB = 32;
constexpr float CUT2  = 25.0f;     // 5.0^2 exact
constexpr int   C     = 15;        // cells/dim; width 80/15 = 5.333 > cutoff
constexpr int   NCP   = 4096;      // padded cell count (3375 used)
constexpr float INVW  = 0.1875f;   // 15/80 exact
constexpr int   QBLOCKS = N / 4;   // 2048 query blocks (4 waves each)

__device__ __forceinline__ int cell_coord(float v) {
    int c = (int)(v * INVW);
    return c > C - 1 ? C - 1 : c;  // v in [0,80): clamp boundary rounding
}

// ---------- build: hist + scan + scatter in one single-block kernel ----------
__global__ __launch_bounds__(1024) void build_kernel(const float* __restrict__ pos,
                                                     int* __restrict__ start_g,
                                                     float4* __restrict__ sorted) {
    __shared__ int cnt[NCP];       // 16 KB: hist, then exclusive starts
    __shared__ int ws[1024];
    const int t = threadIdx.x;

    #pragma unroll
    for (int k = t; k < NCP; k += 1024) cnt[k] = 0;
    __syncthreads();

    int cid[8], rnk[8];
    #pragma unroll
    for (int q = 0; q < 8; ++q) {            // coalesced: i = q*1024 + t
        const int i = q * 1024 + t;
        const int cx = cell_coord(pos[3 * i + 0]);
        const int cy = cell_coord(pos[3 * i + 1]);
        const int cz = cell_coord(pos[3 * i + 2]);
        cid[q] = (cz * C + cy) * C + cx;
        rnk[q] = atomicAdd(&cnt[cid[q]], 1);
    }
    __syncthreads();

    // block-scan of 4096 counts (4 per thread)
    int c[4], pre[4], s = 0;
    #pragma unroll
    for (int k = 0; k < 4; ++k) { c[k] = cnt[4 * t + k]; pre[k] = s; s += c[k]; }
    ws[t] = s;
    __syncthreads();
    for (int off = 1; off < 1024; off <<= 1) {
        const int v = (t >= off) ? ws[t - off] : 0;
        __syncthreads();
        ws[t] += v;
        __syncthreads();
    }
    const int excl = ws[t] - s;
    #pragma unroll
    for (int k = 0; k < 4; ++k) {
        cnt[4 * t + k]     = excl + pre[k];  // in-place: cnt -> exclusive start
        start_g[4 * t + k] = excl + pre[k];
    }
    if (t == 0) start_g[NCP] = N;
    __syncthreads();

    #pragma unroll
    for (int q = 0; q < 8; ++q) {            // atomic-free scatter
        const int i = q * 1024 + t;
        const int p = cnt[cid[q]] + rnk[q];
        sorted[p] = make_float4(pos[3 * i + 0], pos[3 * i + 1], pos[3 * i + 2],
                                __int_as_float(i));
    }
}

// ---------- query: one wave per point, flattened candidates; finalize folded --
__global__ __launch_bounds__(256) void query_kernel(const float* __restrict__ pos,
                                                    const float4* __restrict__ sorted,
                                                    const int* __restrict__ start_g,
                                                    int* __restrict__ out,
                                                    int* __restrict__ out_max) {
    __shared__ int hitbuf[4][64];
    __shared__ int wmax[4];
    const int lane = threadIdx.x & 63;
    const int wave = threadIdx.x >> 6;
    // Force p (and everything derived) into SGPRs: it is wave-uniform.
    const int p = __builtin_amdgcn_readfirstlane((int)blockIdx.x * 4 + wave);

    const float x = pos[3 * p + 0];
    const float y = pos[3 * p + 1];
    const float z = pos[3 * p + 2];
    const int cx = cell_coord(x), cy = cell_coord(y), cz = cell_coord(z);
    // 3 distinct clamped rows per dim; the far row/cell is >= 5.33 away in
    // that dim, so r2 <= 25 rejects all its points (no duplicates, no holes).
    int xa = cx - 1; xa = xa < 0 ? 0 : (xa > C - 3 ? C - 3 : xa);
    int ya = cy - 1; ya = ya < 0 ? 0 : (ya > C - 3 ? C - 3 : ya);
    int za = cz - 1; za = za < 0 ? 0 : (za > C - 3 ? C - 3 : za);

    // Prefetch all 9 segment bounds (wave-uniform -> s_loads, batched).
    int bb[9], pre[10];
    pre[0] = 0;
    #pragma unroll
    for (int s = 0; s < 9; ++s) {
        const int rowb = ((za + s / 3) * C + (ya + s % 3)) * C + xa;
        bb[s] = start_g[rowb];
        pre[s + 1] = pre[s] + (start_g[rowb + 3] - bb[s]);   // 3 x-cells contiguous
    }
    const int total = pre[9];

    int count = 0;                             // full unclamped hit count
    for (int base = 0; base < total; base += 64) {
        const int l = base + lane;
        // Unrolled segment select (cndmask chain; pre/bb stay in SGPRs).
        int idx = 0;
        #pragma unroll
        for (int s = 0; s < 9; ++s) {
            const bool in_s = (l >= pre[s]) && (l < pre[s + 1]);
            idx = in_s ? (bb[s] + (l - pre[s])) : idx;
        }
        const float4 o = sorted[idx];
        // numpy f32 rounding: no FMA, ((dx^2+dy^2)+dz^2)
        const float dx = __fsub_rn(x, o.x);
        const float dy = __fsub_rn(y, o.y);
        const float dz = __fsub_rn(z, o.z);
        const float r2 = __fadd_rn(__fadd_rn(__fmul_rn(dx, dx), __fmul_rn(dy, dy)),
                                   __fmul_rn(dz, dz));
        const int j = __float_as_int(o.w);
        const bool hit = (l < total) && (r2 <= CUT2) && (j != p);
        const unsigned long long m = __ballot(hit);
        if (hit) {
            const int pr = __builtin_amdgcn_mbcnt_hi(
                (unsigned int)(m >> 32),
                __builtin_amdgcn_mbcnt_lo((unsigned int)m, 0u));
            const int slot = count + pr;
            if (slot < 64) hitbuf[wave][slot] = j;
        }
        count += __popcll(m);
    }

    // 64-lane bitonic sort ascending (INT_MAX padding) -> exact argwhere order.
    const int mcount = count < 64 ? count : 64;
    int v = (lane < mcount) ? hitbuf[wave][lane] : 0x7fffffff;
    #pragma unroll
    for (int k = 2; k <= 64; k <<= 1) {
        #pragma unroll
        for (int jj = k >> 1; jj >= 1; jj >>= 1) {
            const int pv = __shfl_xor(v, jj);
            const bool keepmin = ((lane & jj) == 0) == ((lane & k) == 0);
            v = keepmin ? min(v, pv) : max(v, pv);
        }
    }
    if (lane < MAXNB) out[p * MAXNB + lane] = (lane < count) ? v : -1;

    // Zero this block's slice of cell_indices (96 int4 = 1.5 KB, coalesced).
    int4* c4 = (int4*)(out + N * MAXNB) + blockIdx.x * 96;
    if (threadIdx.x < 96) c4[threadIdx.x] = make_int4(0, 0, 0, 0);

    // actual_max: one atomic per block (poison/0 in slot is <= 0: identity).
    if (lane == 0) wmax[wave] = count;
    __syncthreads();
    if (threadIdx.x == 0)
        atomicMax(out_max, max(max(wmax[0], wmax[1]), max(wmax[2], wmax[3])));
}

extern "C" void kernel_launch(void* const* d_in, const int* in_sizes, int n_in,
                              void* d_out, int out_size, void* d_ws, size_t ws_size,
                              hipStream_t stream) {
    const float* pos = (const float*)d_in[0];   // [8192, 3] f32
    int* out = (int*)d_out;
    int* out_max = out + N * MAXNB * 4;         // scalar after to_idx + cell_indices

    // Scratch in d_ws: start_g[0..4096] (reserve 32KB), then sorted[8192] float4.
    int*    start_g = (int*)d_ws;
    float4* sorted  = (float4*)((char*)d_ws + 32768);

    build_kernel<<<1, 1024, 0, stream>>>(pos, start_g, sorted);
    query_kernel<<<QBLOCKS, 256, 0, stream>>>(pos, sorted, start_g, out, out_max);
}

// Round 11
// 74.513 us; speedup vs baseline: 1.2755x; 1.2755x over previous
//
#include <hip/hip_runtime.h>

// OpenBoundary neighbor list, N=8192, cutoff=5.0, max_neighbours=32.
// Outputs (int32, concat): to_idx[8192][32] | cell_indices[8192][32][3]=0 | actual_max
//
// R11 = R9 (77.1us, best) with a faster build:
//   build    (1 block x 1024): LDS hist -> shfl-based scan (2 barriers vs 20)
//            -> atomic-free scatter from registers.
//   query    (8192 waves, one per point): flattened compact candidate list,
//            ballot-compact, 64-lane bitonic sort (= argwhere ascending-j),
//            lanes 0..31 write the row. Block max -> d_ws.
//   finalize (768 blocks): zero cell_indices (3MB) + block 0 reduces maxes
//            (single writer -- NO same-address atomic storm; R8/R10 showed
//            the 2048-block atomicMax fold-in costs ~+17us).

constexpr int   N     = 8192;
constexpr int   MAXNB = 32;
constexpr float CUT2  = 25.0f;     // 5.0^2 exact
constexpr int   C     = 15;        // cells/dim; width 80/15 = 5.333 > cutoff
constexpr int   NCP   = 4096;      // padded cell count (3375 used)
constexpr float INVW  = 0.1875f;   // 15/80 exact
constexpr int   QBLOCKS = N / 4;   // 2048 query blocks (4 waves each)

__device__ __forceinline__ int cell_coord(float v) {
    int c = (int)(v * INVW);
    return c > C - 1 ? C - 1 : c;  // v in [0,80): clamp boundary rounding
}

// ---------- build: hist + shfl-scan + scatter, one single-block kernel ----------
__global__ __launch_bounds__(1024) void build_kernel(const float* __restrict__ pos,
                                                     int* __restrict__ start_g,
                                                     float4* __restrict__ sorted) {
    __shared__ int cnt[NCP];       // 16 KB: hist, then exclusive starts
    __shared__ int wsum[16];       // per-wave totals
    const int t    = threadIdx.x;
    const int lane = t & 63;
    const int wv   = t >> 6;

    #pragma unroll
    for (int k = t; k < NCP; k += 1024) cnt[k] = 0;
    __syncthreads();

    float x[8], y[8], z[8];
    int cid[8], rnk[8];
    #pragma unroll
    for (int q = 0; q < 8; ++q) {            // coalesced: i = q*1024 + t
        const int i = q * 1024 + t;
        x[q] = pos[3 * i + 0];
        y[q] = pos[3 * i + 1];
        z[q] = pos[3 * i + 2];
        cid[q] = (cell_coord(z[q]) * C + cell_coord(y[q])) * C + cell_coord(x[q]);
        rnk[q] = atomicAdd(&cnt[cid[q]], 1);
    }
    __syncthreads();

    // Scan of 4096 counts, 4 per thread: thread-local sum -> wave shfl-scan ->
    // serial 16-entry wave-offset scan -> recombine. 2 barriers total.
    int c[4], pre[4], s0 = 0;
    #pragma unroll
    for (int k = 0; k < 4; ++k) { c[k] = cnt[4 * t + k]; pre[k] = s0; s0 += c[k]; }
    int inc = s0;                            // inclusive prefix within wave
    #pragma unroll
    for (int off = 1; off < 64; off <<= 1) {
        const int v = __shfl_up(inc, off);
        if (lane >= off) inc += v;
    }
    if (lane == 63) wsum[wv] = inc;          // wave total
    __syncthreads();
    if (t == 0) {                            // exclusive scan of 16 wave totals
        int acc = 0;
        #pragma unroll
        for (int k = 0; k < 16; ++k) { const int tmp = wsum[k]; wsum[k] = acc; acc += tmp; }
    }
    __syncthreads();
    const int excl = wsum[wv] + (inc - s0);  // global exclusive thread prefix
    #pragma unroll
    for (int k = 0; k < 4; ++k) {
        cnt[4 * t + k]     = excl + pre[k];  // in-place: cnt -> exclusive start
        start_g[4 * t + k] = excl + pre[k];
    }
    if (t == 0) start_g[NCP] = N;
    __syncthreads();

    #pragma unroll
    for (int q = 0; q < 8; ++q) {            // atomic-free scatter from registers
        const int p = cnt[cid[q]] + rnk[q];
        sorted[p] = make_float4(x[q], y[q], z[q], __int_as_float(q * 1024 + t));
    }
}

// ---------- query: one wave per point, flattened candidate list ----------
__global__ __launch_bounds__(256) void query_kernel(const float* __restrict__ pos,
                                                    const float4* __restrict__ sorted,
                                                    const int* __restrict__ start_g,
                                                    int* __restrict__ out_idx,
                                                    int* __restrict__ blockmax) {
    __shared__ int hitbuf[4][64];
    __shared__ int wmax[4];
    const int lane = threadIdx.x & 63;
    const int wave = threadIdx.x >> 6;
    // Force p (and everything derived) into SGPRs: it is wave-uniform.
    const int p = __builtin_amdgcn_readfirstlane((int)blockIdx.x * 4 + wave);

    const float x = pos[3 * p + 0];
    const float y = pos[3 * p + 1];
    const float z = pos[3 * p + 2];
    const int cx = cell_coord(x), cy = cell_coord(y), cz = cell_coord(z);
    // 3 distinct clamped rows per dim; the far row/cell is >= 5.33 away in
    // that dim, so r2 <= 25 rejects all its points (no duplicates, no holes).
    int xa = cx - 1; xa = xa < 0 ? 0 : (xa > C - 3 ? C - 3 : xa);
    int ya = cy - 1; ya = ya < 0 ? 0 : (ya > C - 3 ? C - 3 : ya);
    int za = cz - 1; za = za < 0 ? 0 : (za > C - 3 ? C - 3 : za);

    // Prefetch all 9 segment bounds (wave-uniform -> s_loads, batched).
    int bb[9], pre[10];
    pre[0] = 0;
    #pragma unroll
    for (int s = 0; s < 9; ++s) {
        const int rowb = ((za + s / 3) * C + (ya + s % 3)) * C + xa;
        bb[s] = start_g[rowb];
        pre[s + 1] = pre[s] + (start_g[rowb + 3] - bb[s]);   // 3 x-cells contiguous
    }
    const int total = pre[9];

    int count = 0;                             // full unclamped hit count
    for (int base = 0; base < total; base += 64) {
        const int l = base + lane;
        // Unrolled segment select (cndmask chain; pre/bb stay in SGPRs).
        int idx = 0;
        #pragma unroll
        for (int s = 0; s < 9; ++s) {
            const bool in_s = (l >= pre[s]) && (l < pre[s + 1]);
            idx = in_s ? (bb[s] + (l - pre[s])) : idx;
        }
        const float4 o = sorted[idx];
        // numpy f32 rounding: no FMA, ((dx^2+dy^2)+dz^2)
        const float dx = __fsub_rn(x, o.x);
        const float dy = __fsub_rn(y, o.y);
        const float dz = __fsub_rn(z, o.z);
        const float r2 = __fadd_rn(__fadd_rn(__fmul_rn(dx, dx), __fmul_rn(dy, dy)),
                                   __fmul_rn(dz, dz));
        const int j = __float_as_int(o.w);
        const bool hit = (l < total) && (r2 <= CUT2) && (j != p);
        const unsigned long long m = __ballot(hit);
        if (hit) {
            const int pr = __builtin_amdgcn_mbcnt_hi(
                (unsigned int)(m >> 32),
                __builtin_amdgcn_mbcnt_lo((unsigned int)m, 0u));
            const int slot = count + pr;
            if (slot < 64) hitbuf[wave][slot] = j;
        }
        count += __popcll(m);
    }

    // 64-lane bitonic sort ascending (INT_MAX padding) -> exact argwhere order.
    const int mcount = count < 64 ? count : 64;
    int v = (lane < mcount) ? hitbuf[wave][lane] : 0x7fffffff;
    #pragma unroll
    for (int k = 2; k <= 64; k <<= 1) {
        #pragma unroll
        for (int jj = k >> 1; jj >= 1; jj >>= 1) {
            const int pv = __shfl_xor(v, jj);
            const bool keepmin = ((lane & jj) == 0) == ((lane & k) == 0);
            v = keepmin ? min(v, pv) : max(v, pv);
        }
    }
    if (lane < MAXNB) out_idx[p * MAXNB + lane] = (lane < count) ? v : -1;

    // per-block max of full counts -> d_ws (count is wave-uniform)
    if (lane == 0) wmax[wave] = count;
    __syncthreads();
    if (threadIdx.x == 0)
        blockmax[blockIdx.x] = max(max(wmax[0], wmax[1]), max(wmax[2], wmax[3]));
}

// ---------- finalize: zero cell_indices + reduce block maxes ----------
__global__ __launch_bounds__(256) void finalize_kernel(int4* __restrict__ cell4,
                                                       const int* __restrict__ blockmax,
                                                       int* __restrict__ out_max) {
    __shared__ int wm[4];
    const int idx = blockIdx.x * 256 + threadIdx.x;
    cell4[idx] = make_int4(0, 0, 0, 0);
    if (blockIdx.x == 0) {
        int mx = 0;
        for (int k = threadIdx.x; k < QBLOCKS; k += 256) mx = max(mx, blockmax[k]);
        #pragma unroll
        for (int off = 32; off > 0; off >>= 1) mx = max(mx, __shfl_down(mx, off));
        if ((threadIdx.x & 63) == 0) wm[threadIdx.x >> 6] = mx;
        __syncthreads();
        if (threadIdx.x == 0)
            *out_max = max(max(wm[0], wm[1]), max(wm[2], wm[3]));
    }
}

extern "C" void kernel_launch(void* const* d_in, const int* in_sizes, int n_in,
                              void* d_out, int out_size, void* d_ws, size_t ws_size,
                              hipStream_t stream) {
    const float* pos = (const float*)d_in[0];   // [8192, 3] f32
    int* out = (int*)d_out;

    int* out_idx = out;                         // [N*32]
    int* base    = out + N * MAXNB;             // cell_indices region (scratch first)
    int* out_max = out + N * MAXNB * 4;         // scalar

    // Scratch inside the 3MB cell_indices region (zeroed by finalize):
    int*    start_g  = base;                    // [0, 4097)
    float4* sorted   = (float4*)(base + 8192);  // 16B aligned (base is 1MB into d_out)
    int*    blockmax = (int*)d_ws;              // [2048] ints; fully written by query

    build_kernel   <<<1, 1024, 0, stream>>>(pos, start_g, sorted);
    query_kernel   <<<QBLOCKS, 256, 0, stream>>>(pos, sorted, start_g, out_idx, blockmax);
    finalize_kernel<<<N * MAXNB * 3 / 4 / 256, 256, 0, stream>>>((int4*)base, blockmax, out_max);
}